// Round 1
// baseline (583.245 us; speedup 1.0000x reference)
//
#include <hip/hip_runtime.h>
#include <math.h>

// Problem constants: H=300, D=600, B=256 graphs, Nu=Nv=8192, batch SORTED.
#define HDIM 300
#define DDIM 600
#define NGR  256

typedef float vf4 __attribute__((ext_vector_type(4)));
typedef float vf2 __attribute__((ext_vector_type(2)));

__device__ __forceinline__ float wred_sum(float v){
  #pragma unroll
  for(int o=32;o;o>>=1) v += __shfl_xor(v,o,64);
  return v;
}
__device__ __forceinline__ float wred_max(float v){
  #pragma unroll
  for(int o=32;o;o>>=1) v = fmaxf(v,__shfl_xor(v,o,64));
  return v;
}
__device__ __forceinline__ float sigm(float x){ return 1.f/(1.f+expf(-x)); }

// Zero-fill map row i outside its in-graph span [js,je) (NT float4 stores).
__device__ __forceinline__ void fill_row(int i, const int* __restrict__ ub,
    const int* __restrict__ voff, float* __restrict__ mapbase, int Nv, int tid){
  int g = ub[i];
  int js = voff[g], je = voff[g+1];
  float* mrow = mapbase + (size_t)i*Nv;
  const vf4 z4 = {0.f,0.f,0.f,0.f};
  int nf4 = Nv >> 2;
  for (int q4=tid; q4<nf4; q4+=256){
    int j0 = q4*4;
    if (j0+4 <= js || j0 >= je){
      __builtin_nontemporal_store(z4, (vf4*)(mrow + j0));
    } else {
      #pragma unroll
      for(int u=0;u<4;u++){ int j=j0+u; if (j<js || j>=je) mrow[j]=0.f; }
    }
  }
}

// ---- K1: blocks [0,NBn): l2-normalize rows (4 waves/block);
//  NBn: offsets (binary search) + step-1 LSTM closed form + out init;
//  (NBn, NBn+600]: gbase (recomputes bias-only h1 locally -> no cross-block dep).
__global__ __launch_bounds__(256) void k_norm_off(const float* __restrict__ xu,
    const float* __restrict__ xv, float* __restrict__ su, float* __restrict__ sv,
    int Nu, int Nv, const int* __restrict__ ub, const int* __restrict__ vb,
    int* __restrict__ uoff, int* __restrict__ voff,
    const float* __restrict__ b_ih, const float* __restrict__ b_hh,
    float* __restrict__ h1, float* __restrict__ c1,
    const float* __restrict__ pb, float* __restrict__ outp,
    const float* __restrict__ Wih, const float* __restrict__ Whh,
    float* __restrict__ gbase){
  int NBn = (Nu + Nv) >> 2;
  int b = blockIdx.x;
  int tid = threadIdx.x, lane = tid & 63, w = tid >> 6;
  if (b == NBn){
    int t = tid;
    if (t < NGR){
      int lo=0, hi=Nu;
      while(lo<hi){ int m=(lo+hi)>>1; if (ub[m] < t) lo=m+1; else hi=m; }
      uoff[t]=lo;
      lo=0; hi=Nv;
      while(lo<hi){ int m=(lo+hi)>>1; if (vb[m] < t) lo=m+1; else hi=m; }
      voff[t]=lo;
      if (t==0){ uoff[NGR]=Nu; voff[NGR]=Nv; }
      outp[t] = pb[0];
    }
    for (int d=tid; d<DDIM; d+=256){
      float gi = b_ih[d]      + b_hh[d];
      float gg = b_ih[1200+d] + b_hh[1200+d];
      float go = b_ih[1800+d] + b_hh[1800+d];
      float c  = sigm(gi)*tanhf(gg);       // f*c0 = 0
      c1[d]=c; h1[d]=sigm(go)*tanhf(c);
    }
    return;
  }
  if (b > NBn){                            // gbase blocks
    __shared__ float h1l[DDIM];
    for (int d=tid; d<DDIM; d+=256){       // recompute bias-only h1 locally
      float gi = b_ih[d]      + b_hh[d];
      float gg = b_ih[1200+d] + b_hh[1200+d];
      float go = b_ih[1800+d] + b_hh[1800+d];
      float c  = sigm(gi)*tanhf(gg);
      h1l[d]   = sigm(go)*tanhf(c);
    }
    __syncthreads();
    int n = (b - NBn - 1)*4 + w;           // 600 blocks x 4 waves = 2400 rows
    const float* wi = Wih + (size_t)n*1200;
    const float* wh = Whh + (size_t)n*600;
    float s = 0.f;
    for (int k=lane; k<DDIM; k+=64) s += h1l[k]*(wi[k] + wh[k]);
    s = wred_sum(s);
    if (lane==0) gbase[n] = s + b_ih[n] + b_hh[n];
    return;
  }
  int wid = b*4 + w;
  const float* src; float* dst;
  if (wid < Nu){ src = xu + (size_t)wid*HDIM; dst = su + (size_t)wid*HDIM; }
  else         { src = xv + (size_t)(wid-Nu)*HDIM; dst = sv + (size_t)(wid-Nu)*HDIM; }
  const vf4* s4 = (const vf4*)src;
  vf4 A = s4[lane];
  vf4 Bv = (lane<11)? s4[64+lane] : (vf4){0.f,0.f,0.f,0.f};
  float s = A.x*A.x+A.y*A.y+A.z*A.z+A.w*A.w + Bv.x*Bv.x+Bv.y*Bv.y+Bv.z*Bv.z+Bv.w*Bv.w;
  s = wred_sum(s);
  float inv = 1.f / fmaxf(sqrtf(s), 1e-12f);
  vf4* d4 = (vf4*)dst;
  d4[lane] = A*inv;
  if (lane<11) d4[64+lane] = Bv*inv;
}

// ---- K2': per-graph-side compute (512 blocks) interleaved 1:16 with the 8192
// map-fill blocks (fill stays in the big kernel per R7 evidence).
// Compute block (g, set): stage partner rows (<=32 at a time) in LDS once,
// lane-per-partner-column dots (NO per-dot shuffle reduce, NO per-dot global
// loads), coalesced 128B map stores, primes accumulated in registers, then
// e1 -> segment softmax -> r1 finished in-block (replaces old K3 entirely).
__global__ __launch_bounds__(256) void k_graph(
    const float* __restrict__ su, const float* __restrict__ sv,
    const int* __restrict__ ub,
    const int* __restrict__ uoff, const int* __restrict__ voff,
    float* __restrict__ spr, float* __restrict__ svp,
    float* __restrict__ e1u, float* __restrict__ e1v,
    const float* __restrict__ h1, float* __restrict__ mapbase,
    float* __restrict__ r1, int Nv){
  int b = blockIdx.x;
  int tid = threadIdx.x, lane = tid & 63, w = tid >> 6;
  int P = (gridDim.x + 511) >> 9;          // ceil(T/512): compute every P-th block
  int q = b / P;
  if ((b % P) != 0 || q >= 512){           // fill block
    int nb_comp = (b % P) ? (q + 1) : q;   // compute blocks strictly before b
    if (nb_comp > 512) nb_comp = 512;
    fill_row(b - nb_comp, ub, voff, mapbase, Nv, tid);
    return;
  }
  int cid = q;                             // 0..511
  int set = cid & 1, g = cid >> 1;
  const float* xown = set ? sv  : su;
  const float* xpar = set ? su  : sv;
  const int*   ooff = set ? voff: uoff;
  const int*   poff = set ? uoff: voff;
  float* prime = set ? svp : spr;
  float* e1g   = set ? e1v : e1u;
  int us = ooff[g], ue = ooff[g+1];
  int ps = poff[g], pe = poff[g+1];
  int n = ue - us, np = pe - ps;

  // LDS: partner chunk (32 rows, stride 308 floats: 16B aligned, 4-way banks)
  __shared__ __align__(16) float SVl[32*308];   // 39.4 KB
  __shared__ __align__(16) float XUl[8*308];    //  9.9 KB (8 own rows / pass)
  __shared__ __align__(16) float Ql[608];       //  q = h1 (600)
  __shared__ float e1l[256];
  __shared__ float al[256];
  __shared__ float red[4];
  __shared__ float shv;

  for (int t=tid; t<DDIM; t+=256) Ql[t] = h1[t];
  bool single = (np <= 32);                // common case: whole partner set fits
  if (single){
    for (int idx=tid; idx<np*HDIM; idx+=256){
      int r = idx/HDIM, c = idx - r*HDIM;
      SVl[r*308+c] = xpar[(size_t)(ps+r)*HDIM + c];
    }
  }
  const vf4* SV4 = (const vf4*)SVl;
  const vf4* XU4 = (const vf4*)XUl;
  const vf4* Q4  = (const vf4*)Ql;
  int jj = lane & 31, half = lane >> 5;

  int passes = (n + 7) >> 3;               // 8 own rows per pass (2 per wave)
  for (int p=0; p<passes; p++){
    int i0 = us + p*8;
    int nr = min(8, ue - i0);
    __syncthreads();                       // prior pass done reading XU8/SV
    for (int idx=tid; idx<nr*HDIM; idx+=256){
      int r = idx/HDIM, c = idx - r*HDIM;
      XUl[r*308+c] = xown[(size_t)(i0+r)*HDIM + c];
    }
    if (!single){                          // restage chunk 0 each pass
      int nc0 = np < 32 ? np : 32;
      for (int idx=tid; idx<nc0*HDIM; idx+=256){
        int r = idx/HDIM, c = idx - r*HDIM;
        SVl[r*308+c] = xpar[(size_t)(ps+r)*HDIM + c];
      }
    }
    __syncthreads();

    int lr = 2*w + half;                   // this lane's own row (0..7)
    int gi = i0 + lr;
    bool rv = (lr < nr);
    vf4 prA0={0,0,0,0}, prB0={0,0,0,0}, prA1={0,0,0,0}, prB1={0,0,0,0};

    for (int cs = ps, ci = 0; cs < pe; cs += 32, ci++){
      int nc = min(32, pe - cs);
      if (!single && ci > 0){
        __syncthreads();
        for (int idx=tid; idx<nc*HDIM; idx+=256){
          int r = idx/HDIM, c = idx - r*HDIM;
          SVl[r*308+c] = xpar[(size_t)(cs+r)*HDIM + c];
        }
        __syncthreads();
      }
      // dot phase: lane computes full 300-dot of own row lr vs partner cs+jj.
      float d = 0.f;
      const vf4* svr = SV4 + jj*77;
      const vf4* xr4 = XU4 + lr*77;
      for (int c4=0; c4<75; c4++){
        vf4 s4 = svr[c4], x4 = xr4[c4];
        d += s4.x*x4.x + s4.y*x4.y + s4.z*x4.z + s4.w*x4.w;
      }
      // coalesced map store (u-side only): lanes 0..31 -> 128B line per row.
      if (set==0 && rv && jj<nc) mapbase[(size_t)gi*Nv + (cs+jj)] = d;
      // prime accumulate: broadcast d's from lanes via shfl, FMA over c-slices.
      for (int j=0; j<nc; j++){
        float d0 = __shfl(d, j);       // row 2w
        float d1 = __shfl(d, 32+j);    // row 2w+1
        vf4 sA = SV4[j*77 + lane];
        vf4 sB = (lane<11)? SV4[j*77 + 64 + lane] : (vf4){0,0,0,0};
        prA0 += d0*sA; prB0 += d0*sB;
        prA1 += d1*sA; prB1 += d1*sB;
      }
    }

    // e1 + prime/e1 stores for this pass's two rows per wave.
    int r0 = 2*w;
    bool rv0 = (r0   < nr);
    bool rv1 = (r0+1 < nr);
    if (rv0){
      int gi0 = i0 + r0;
      vf4 xA = XU4[r0*77 + lane];
      vf4 qA = Q4[lane], q2A = Q4[75+lane];
      float ep = xA.x*qA.x+xA.y*qA.y+xA.z*qA.z+xA.w*qA.w
               + prA0.x*q2A.x+prA0.y*q2A.y+prA0.z*q2A.z+prA0.w*q2A.w;
      if (lane<11){
        vf4 xB = XU4[r0*77+64+lane];
        vf4 qB = Q4[64+lane], q2B = Q4[139+lane];
        ep += xB.x*qB.x+xB.y*qB.y+xB.z*qB.z+xB.w*qB.w
            + prB0.x*q2B.x+prB0.y*q2B.y+prB0.z*q2B.z+prB0.w*q2B.w;
      }
      ep = wred_sum(ep);
      vf4* p4 = (vf4*)(prime + (size_t)gi0*HDIM);
      p4[lane] = prA0;
      if (lane<11) p4[64+lane] = prB0;
      if (lane==0){ int t = gi0-us; if (t<256) e1l[t]=ep; else e1g[gi0]=ep; }
    }
    if (rv1){
      int gi1 = i0 + r0 + 1;
      vf4 xA = XU4[(r0+1)*77 + lane];
      vf4 qA = Q4[lane], q2A = Q4[75+lane];
      float ep = xA.x*qA.x+xA.y*qA.y+xA.z*qA.z+xA.w*qA.w
               + prA1.x*q2A.x+prA1.y*q2A.y+prA1.z*q2A.z+prA1.w*q2A.w;
      if (lane<11){
        vf4 xB = XU4[(r0+1)*77+64+lane];
        vf4 qB = Q4[64+lane], q2B = Q4[139+lane];
        ep += xB.x*qB.x+xB.y*qB.y+xB.z*qB.z+xB.w*qB.w
            + prB1.x*q2B.x+prB1.y*q2B.y+prB1.z*q2B.z+prB1.w*q2B.w;
      }
      ep = wred_sum(ep);
      vf4* p4 = (vf4*)(prime + (size_t)gi1*HDIM);
      p4[lane] = prA1;
      if (lane<11) p4[64+lane] = prB1;
      if (lane==0){ int t = gi1-us; if (t<256) e1l[t]=ep; else e1g[gi1]=ep; }
    }
  }

  // ---- segment softmax + r1 (former K3), all e1 in LDS (overflow -> e1g).
  __syncthreads();
  float m = -INFINITY;
  for (int t=tid; t<n; t+=256) m = fmaxf(m, (t<256)? e1l[t] : e1g[us+t]);
  m = wred_max(m);
  if (lane==0) red[w]=m;
  __syncthreads();
  if (tid==0) shv = fmaxf(fmaxf(red[0],red[1]),fmaxf(red[2],red[3]));
  __syncthreads();
  float emax = shv;
  float s = 0.f;
  for (int t=tid; t<n; t+=256){
    float a = expf(((t<256)? e1l[t] : e1g[us+t]) - emax);
    if (t<256) al[t]=a; else e1g[us+t]=a;
    s += a;
  }
  s = wred_sum(s);
  __syncthreads();
  if (lane==0) red[w]=s;
  __syncthreads();
  if (tid==0) shv = red[0]+red[1]+red[2]+red[3];
  __syncthreads();
  float inv = 1.f/(shv + 1e-16f);
  float acc[3] = {0.f,0.f,0.f};
  #pragma unroll 4
  for (int nn=0; nn<n; nn++){
    float a = (nn<256)? al[nn] : e1g[us+nn];
    const float* xr = xown  + (size_t)(us+nn)*HDIM;
    const float* pp = prime + (size_t)(us+nn)*HDIM;
    #pragma unroll
    for(int u=0;u<3;u++){ int c = tid + u*256; if (c<DDIM){
        float xv = (c<HDIM)? xr[c] : pp[c-HDIM]; acc[u] += a*xv; } }
  }
  int bs = (set<<8) | g;
  #pragma unroll
  for(int u=0;u<3;u++){ int c = tid + u*256; if (c<DDIM) r1[(size_t)bs*DDIM + c] = acc[u]*inv; }
}

// ---- K4: fused GEMM (gates = r1 @ Wih[:,600:].T) + step-2 LSTM pointwise.
// 32 gs x 64 col tile (cols = 4 gates x 16 d), grid 38x16 = 608 blocks. -----
__global__ __launch_bounds__(256) void k_gemm_lstm(const float* __restrict__ r1,
    const float* __restrict__ Wih, const float* __restrict__ gbase,
    const float* __restrict__ c1, float* __restrict__ h2){
  __shared__ __align__(16) float smem[32*68];   // gates phase; K phase aliases
  float* Al = smem;            // 16*36
  float* Bl = smem + 16*36;    // 16*68
  int tid = threadIdx.x;
  int d0  = blockIdx.x*16;     // 38 blocks: d0 = 0..592 (last has 8 valid)
  int gs0 = blockIdx.y*32;
  int tx = tid & 15, ty = tid >> 4;
  float acc[2][4] = {};
  for (int kt=0; kt<600; kt+=16){
    int k = kt + tx;
    bool kok = (k < 600);
    #pragma unroll
    for (int u=0; u<2; u++){
      int rl = ty + u*16;
      Al[tx*36 + rl] = kok ? r1[(size_t)(gs0+rl)*DDIM + k] : 0.f;
    }
    #pragma unroll
    for (int u=0; u<4; u++){
      int cl = ty + u*16;                 // 0..63
      int gate = cl >> 4, dd = cl & 15;
      int d = d0 + dd;
      Bl[tx*68 + cl] = (kok && d < 600)
          ? Wih[(size_t)(gate*600 + d)*1200 + 600 + k] : 0.f;
    }
    __syncthreads();
    #pragma unroll
    for (int kk=0; kk<16; kk++){
      vf2 av = ((const vf2*)(Al + kk*36))[ty];
      vf4 bv = ((const vf4*)(Bl + kk*68))[tx];
      float a[2]={av.x,av.y}, bb[4]={bv.x,bv.y,bv.z,bv.w};
      #pragma unroll
      for(int mm=0;mm<2;mm++)
        #pragma unroll
        for(int nn=0;nn<4;nn++) acc[mm][nn] += a[mm]*bb[nn];
    }
    __syncthreads();
  }
  #pragma unroll
  for (int mm=0; mm<2; mm++){
    vf4 o = {acc[mm][0], acc[mm][1], acc[mm][2], acc[mm][3]};
    ((vf4*)(smem + (ty*2+mm)*68))[tx] = o;
  }
  __syncthreads();
  int d_l = tid & 15, r0 = tid >> 4;
  int d = d0 + d_l;
  if (d < 600){
    float gb_i = gbase[d], gb_f = gbase[600+d], gb_g = gbase[1200+d], gb_o = gbase[1800+d];
    float cc1 = c1[d];
    #pragma unroll
    for (int u=0; u<2; u++){
      int rl = r0 + u*16;
      const float* gr = smem + rl*68;
      float gi = gr[d_l]      + gb_i;
      float gf = gr[16+d_l]   + gb_f;
      float gG = gr[32+d_l]   + gb_g;
      float go = gr[48+d_l]   + gb_o;
      float c  = sigm(gf)*cc1 + sigm(gi)*tanhf(gG);
      h2[(size_t)(gs0+rl)*DDIM + d] = sigm(go)*tanhf(c);
    }
  }
}

// ---- K5: 512 blocks: e2 (in LDS) -> segment softmax -> r2 -> atomicAdd pred
__global__ __launch_bounds__(256) void k_r2(const float* __restrict__ su,
    const float* __restrict__ sv, const float* __restrict__ spr,
    const float* __restrict__ svp, const int* __restrict__ uoff,
    const int* __restrict__ voff, const float* __restrict__ h2,
    const float* __restrict__ pW, float* __restrict__ e2u,
    float* __restrict__ e2v, float* __restrict__ outp){
  int tid = threadIdx.x, lane = tid & 63, w = tid >> 6;
  int bs = blockIdx.x; int set = bs >> 8; int g = bs & 255;
  const float* x  = set? sv  : su;
  const float* pr = set? svp : spr;
  const int* off  = set? voff: uoff;
  float* e2g      = set? e2v : e2u;        // overflow fallback only
  __shared__ float q[DDIM]; __shared__ float e2l[128]; __shared__ float al[128];
  __shared__ float red[4]; __shared__ float shv;
  for (int t=tid; t<DDIM; t+=256) q[t] = h2[(size_t)bs*DDIM + t];
  int ns = off[g], ne = off[g+1]; int n = ne - ns;
  __syncthreads();
  #pragma unroll 2
  for (int node = ns + w; node < ne; node += 4){
    const float* xr = x  + (size_t)node*HDIM;
    const float* pp = pr + (size_t)node*HDIM;
    float d = 0.f;
    #pragma unroll
    for(int c=0;c<10;c++){ int k = lane + 64*c; if (k<DDIM){
        float xv = (k<HDIM)? xr[k] : pp[k-HDIM]; d += xv*q[k]; } }
    d = wred_sum(d);
    if (lane==0){ int t = node-ns; if (t<128) e2l[t] = d; else e2g[node] = d; }
  }
  __syncthreads();
  float m = -INFINITY;
  for (int t=tid; t<n; t+=256) m = fmaxf(m, (t<128)? e2l[t] : e2g[ns+t]);
  m = wred_max(m);
  if (lane==0) red[w]=m;
  __syncthreads();
  if (tid==0) shv = fmaxf(fmaxf(red[0],red[1]),fmaxf(red[2],red[3]));
  __syncthreads();
  float emax = shv;
  float s = 0.f;
  for (int t=tid; t<n; t+=256){
    float a = expf(((t<128)? e2l[t] : e2g[ns+t]) - emax);
    if (t<128) al[t]=a; else e2g[ns+t]=a;
    s += a;
  }
  s = wred_sum(s);
  __syncthreads();
  if (lane==0) red[w]=s;
  __syncthreads();
  if (tid==0) shv = red[0]+red[1]+red[2]+red[3];
  __syncthreads();
  float inv = 1.f/(shv + 1e-16f);
  float acc[3] = {0.f,0.f,0.f};
  #pragma unroll 4
  for (int nn=0; nn<n; nn++){
    float a = (nn<128)? al[nn] : e2g[ns+nn];
    const float* xr = x  + (size_t)(ns+nn)*HDIM;
    const float* pp = pr + (size_t)(ns+nn)*HDIM;
    #pragma unroll
    for(int u=0;u<3;u++){ int c = tid + u*256; if (c<DDIM){
        float xv = (c<HDIM)? xr[c] : pp[c-HDIM]; acc[u] += a*xv; } }
  }
  int hoff = set? 1200 : 0;
  float p = 0.f;
  #pragma unroll
  for(int u=0;u<3;u++){ int c = tid + u*256; if (c<DDIM) p += (acc[u]*inv)*pW[hoff+600+c]; }
  for (int t=tid; t<DDIM; t+=256) p += q[t]*pW[hoff+t];
  p = wred_sum(p);
  __syncthreads();
  if (lane==0) red[w] = p;
  __syncthreads();
  if (tid==0) atomicAdd(&outp[g], red[0]+red[1]+red[2]+red[3]);
}

extern "C" void kernel_launch(void* const* d_in, const int* in_sizes, int n_in,
                              void* d_out, int out_size, void* d_ws, size_t ws_size,
                              hipStream_t stream) {
  const float* solute_x  = (const float*)d_in[0];
  const float* solvent_x = (const float*)d_in[1];
  const int*   ub        = (const int*)d_in[2];
  const int*   vb        = (const int*)d_in[3];
  const float* Wih  = (const float*)d_in[5];
  const float* Whh  = (const float*)d_in[6];
  const float* b_ih = (const float*)d_in[7];
  const float* b_hh = (const float*)d_in[8];
  const float* pW   = (const float*)d_in[9];
  const float* pb   = (const float*)d_in[10];

  int Nu = in_sizes[0] / HDIM;
  int Nv = in_sizes[1] / HDIM;

  float* out = (float*)d_out;
  int predn = out_size - Nu*Nv;        // = 256
  float* mapbase = out + predn;

  float* ws = (float*)d_ws;
  float* su    = ws;
  float* sv    = su    + (size_t)Nu*HDIM;
  float* spr   = sv    + (size_t)Nv*HDIM;
  float* svp   = spr   + (size_t)Nu*HDIM;
  float* e1u   = svp   + (size_t)Nv*HDIM;  // Nu (k_graph overflow / K5 scratch)
  float* e1v   = e1u   + Nu;               // Nv
  float* h1    = e1v   + Nv;               // 600
  float* c1    = h1    + DDIM;             // 600
  float* r1    = c1    + DDIM;             // 512*600
  float* gbase = r1    + 512*DDIM;         // 2400
  float* h2    = gbase + 2400;             // 512*600
  int*   uoff  = (int*)(h2 + 512*DDIM);    // 257
  int*   voff  = uoff + 257;               // 257

  k_norm_off<<<dim3((Nu+Nv)/4 + 1 + 600), dim3(256), 0, stream>>>(
      solute_x, solvent_x, su, sv, Nu, Nv, ub, vb, uoff, voff,
      b_ih, b_hh, h1, c1, pb, out, Wih, Whh, gbase);
  // 512 compute blocks interleaved with Nu fill blocks.
  k_graph<<<dim3(Nu + 512), dim3(256), 0, stream>>>(
      su, sv, ub, uoff, voff, spr, svp, e1u, e1v, h1, mapbase, r1, Nv);
  k_gemm_lstm<<<dim3(38, 16), dim3(256), 0, stream>>>(r1, Wih, gbase, c1, h2);
  k_r2<<<dim3(512), dim3(256), 0, stream>>>(
      su, sv, spr, svp, uoff, voff, h2, pW, e1u, e1v, out);
}

// Round 2
// 569.073 us; speedup vs baseline: 1.0249x; 1.0249x over previous
//
#include <hip/hip_runtime.h>
#include <math.h>

// Problem constants: H=300, D=600, B=256 graphs, Nu=Nv=8192, batch SORTED.
#define HDIM 300
#define DDIM 600
#define NGR  256

typedef float vf4 __attribute__((ext_vector_type(4)));
typedef float vf2 __attribute__((ext_vector_type(2)));

__device__ __forceinline__ float wred_sum(float v){
  #pragma unroll
  for(int o=32;o;o>>=1) v += __shfl_xor(v,o,64);
  return v;
}
__device__ __forceinline__ float wred_max(float v){
  #pragma unroll
  for(int o=32;o;o>>=1) v = fmaxf(v,__shfl_xor(v,o,64));
  return v;
}
__device__ __forceinline__ float sigm(float x){ return 1.f/(1.f+expf(-x)); }

// Zero-fill map row i outside its in-graph span [js,je) (NT float4 stores).
__device__ __forceinline__ void fill_row(int i, const int* __restrict__ ub,
    const int* __restrict__ voff, float* __restrict__ mapbase, int Nv, int tid){
  int g = ub[i];
  int js = voff[g], je = voff[g+1];
  float* mrow = mapbase + (size_t)i*Nv;
  const vf4 z4 = {0.f,0.f,0.f,0.f};
  int nf4 = Nv >> 2;
  for (int q4=tid; q4<nf4; q4+=256){
    int j0 = q4*4;
    if (j0+4 <= js || j0 >= je){
      __builtin_nontemporal_store(z4, (vf4*)(mrow + j0));
    } else {
      #pragma unroll
      for(int u=0;u<4;u++){ int j=j0+u; if (j<js || j>=je) mrow[j]=0.f; }
    }
  }
}

// ---- K1: blocks [0,NBn): l2-normalize rows (4 waves/block);
//  NBn: offsets (binary search) + step-1 LSTM closed form + out init;
//  (NBn, NBn+600]: gbase (recomputes bias-only h1 locally -> no cross-block dep).
__global__ __launch_bounds__(256) void k_norm_off(const float* __restrict__ xu,
    const float* __restrict__ xv, float* __restrict__ su, float* __restrict__ sv,
    int Nu, int Nv, const int* __restrict__ ub, const int* __restrict__ vb,
    int* __restrict__ uoff, int* __restrict__ voff,
    const float* __restrict__ b_ih, const float* __restrict__ b_hh,
    float* __restrict__ h1, float* __restrict__ c1,
    const float* __restrict__ pb, float* __restrict__ outp,
    const float* __restrict__ Wih, const float* __restrict__ Whh,
    float* __restrict__ gbase){
  int NBn = (Nu + Nv) >> 2;
  int b = blockIdx.x;
  int tid = threadIdx.x, lane = tid & 63, w = tid >> 6;
  if (b == NBn){
    int t = tid;
    if (t < NGR){
      int lo=0, hi=Nu;
      while(lo<hi){ int m=(lo+hi)>>1; if (ub[m] < t) lo=m+1; else hi=m; }
      uoff[t]=lo;
      lo=0; hi=Nv;
      while(lo<hi){ int m=(lo+hi)>>1; if (vb[m] < t) lo=m+1; else hi=m; }
      voff[t]=lo;
      if (t==0){ uoff[NGR]=Nu; voff[NGR]=Nv; }
      outp[t] = pb[0];
    }
    for (int d=tid; d<DDIM; d+=256){
      float gi = b_ih[d]      + b_hh[d];
      float gg = b_ih[1200+d] + b_hh[1200+d];
      float go = b_ih[1800+d] + b_hh[1800+d];
      float c  = sigm(gi)*tanhf(gg);       // f*c0 = 0
      c1[d]=c; h1[d]=sigm(go)*tanhf(c);
    }
    return;
  }
  if (b > NBn){                            // gbase blocks
    __shared__ float h1l[DDIM];
    for (int d=tid; d<DDIM; d+=256){       // recompute bias-only h1 locally
      float gi = b_ih[d]      + b_hh[d];
      float gg = b_ih[1200+d] + b_hh[1200+d];
      float go = b_ih[1800+d] + b_hh[1800+d];
      float c  = sigm(gi)*tanhf(gg);
      h1l[d]   = sigm(go)*tanhf(c);
    }
    __syncthreads();
    int n = (b - NBn - 1)*4 + w;           // 600 blocks x 4 waves = 2400 rows
    const float* wi = Wih + (size_t)n*1200;
    const float* wh = Whh + (size_t)n*600;
    float s = 0.f;
    for (int k=lane; k<DDIM; k+=64) s += h1l[k]*(wi[k] + wh[k]);
    s = wred_sum(s);
    if (lane==0) gbase[n] = s + b_ih[n] + b_hh[n];
    return;
  }
  int wid = b*4 + w;
  const float* src; float* dst;
  if (wid < Nu){ src = xu + (size_t)wid*HDIM; dst = su + (size_t)wid*HDIM; }
  else         { src = xv + (size_t)(wid-Nu)*HDIM; dst = sv + (size_t)(wid-Nu)*HDIM; }
  const vf4* s4 = (const vf4*)src;
  vf4 A = s4[lane];
  vf4 Bv = (lane<11)? s4[64+lane] : (vf4){0.f,0.f,0.f,0.f};
  float s = A.x*A.x+A.y*A.y+A.z*A.z+A.w*A.w + Bv.x*Bv.x+Bv.y*Bv.y+Bv.z*Bv.z+Bv.w*Bv.w;
  s = wred_sum(s);
  float inv = 1.f / fmaxf(sqrtf(s), 1e-12f);
  vf4* d4 = (vf4*)dst;
  d4[lane] = A*inv;
  if (lane<11) d4[64+lane] = Bv*inv;
}

// ---- K2'': one WAVE per own-row pair. 2048 compute blocks (4 indep waves
// each, NO block barriers, ~10KB LDS) interleaved 1:4 with 8192 fill blocks.
// R1 lesson: 54KB-LDS fused kernel -> 2-3 blocks/CU -> 11% occupancy -> 203us.
// This keeps R0's proven scheduling shape (many small low-LDS blocks) while
// fixing R0-K2's inner loop: full-dot-per-lane (no 6-shfl chain per dot),
// partner row read once per dot + once coalesced for prime, 256B map stores.
__global__ __launch_bounds__(256) void k_pair(
    const float* __restrict__ su, const float* __restrict__ sv,
    const int* __restrict__ ub, const int* __restrict__ vb,
    const int* __restrict__ uoff, const int* __restrict__ voff,
    float* __restrict__ spr, float* __restrict__ svp,
    float* __restrict__ e1u, float* __restrict__ e1v,
    const float* __restrict__ h1, float* __restrict__ mapbase,
    int Nu, int Nv){
  int b = blockIdx.x, tid = threadIdx.x, lane = tid & 63, w = tid >> 6;
  int ncomp = (Nu + Nv) >> 3;              // 2048 compute blocks (8 rows each)
  int P = gridDim.x / ncomp;               // interleave period (=5)
  int q = b / P;
  if ((b % P) != 0 || q >= ncomp){         // fill block
    int nb = (b % P) ? (q + 1) : q;        // compute blocks strictly before b
    if (nb > ncomp) nb = ncomp;
    fill_row(b - nb, ub, voff, mapbase, Nv, tid);
    return;
  }
  int p  = q*4 + w;                        // pair id: rows 2p, 2p+1
  int r0 = 2*p;
  bool isU = (r0 < Nu);
  int i0 = isU ? r0 : r0 - Nu;
  const float* xown = isU ? su : sv;
  const float* xpar = isU ? sv : su;
  const int* batch  = isU ? ub : vb;
  const int* poff   = isU ? voff : uoff;
  float* prime      = isU ? spr : svp;
  float* e1g        = isU ? e1u : e1v;

  // wave-private own-pair in LDS (stride 308 floats: 16B aligned, low conflict)
  __shared__ __align__(16) float XS[4][2*308];
  float* X = XS[w];
  for (int t=lane; t<2*HDIM; t+=64){       // rows contiguous in global
    int rr = t / HDIM, c = t - rr*HDIM;
    X[rr*308 + c] = xown[(size_t)i0*HDIM + t];
  }
  int g0 = batch[i0], g1 = batch[i0+1];
  int ngrp = (g0==g1) ? 1 : 2;             // pair may straddle a graph boundary
  const vf4* H4  = (const vf4*)h1;         // q1 = h1[0:300]
  const vf4* H4b = (const vf4*)(h1 + HDIM);// q2 = h1[300:600]

  for (int grp=0; grp<ngrp; grp++){
    int g  = grp ? g1 : g0;
    int rA = (ngrp==2) ? grp : 0;          // first row of this group
    int has2 = (ngrp==1) ? 1 : 0;          // group covers rows rA..rA+has2
    int ps = poff[g], pe = poff[g+1];
    const vf4* X0 = (const vf4*)(X + rA*308);
    const vf4* X1 = (const vf4*)(X + (rA+1)*308);
    vf4 pA0={0,0,0,0}, pB0={0,0,0,0}, pA1={0,0,0,0}, pB1={0,0,0,0};
    for (int cs=ps; cs<pe; cs+=64){
      int nc = min(64, pe-cs);
      // dot phase: lane owns partner cs+lane, full 300-dot vs rows rA(,rA+1).
      // X reads are wave-broadcast (conflict-free); partner stream is one
      // vf4/lane walking its own row (lines fully consumed across c4).
      float d0 = 0.f, d1 = 0.f;
      if (lane < nc){
        const vf4* pr = (const vf4*)(xpar + (size_t)(cs+lane)*HDIM);
        #pragma unroll 5
        for (int c4=0; c4<75; c4++){
          vf4 pv = pr[c4];
          vf4 x0 = X0[c4];
          d0 += pv.x*x0.x + pv.y*x0.y + pv.z*x0.z + pv.w*x0.w;
          if (has2){
            vf4 x1 = X1[c4];
            d1 += pv.x*x1.x + pv.y*x1.y + pv.z*x1.z + pv.w*x1.w;
          }
        }
      }
      if (isU && lane < nc){               // coalesced 256B map lines
        mapbase[(size_t)(i0+rA)*Nv + (cs+lane)] = d0;
        if (has2) mapbase[(size_t)(i0+rA+1)*Nv + (cs+lane)] = d1;
      }
      // prime accumulate: 2 shfl per partner, coalesced partner re-read (L2).
      for (int j=0; j<nc; j++){
        float dj0 = __shfl(d0, j);
        float dj1 = has2 ? __shfl(d1, j) : 0.f;
        const vf4* pr = (const vf4*)(xpar + (size_t)(cs+j)*HDIM);
        vf4 a  = pr[lane];
        vf4 bb = (lane<11) ? pr[64+lane] : (vf4){0.f,0.f,0.f,0.f};
        pA0 += dj0*a; pB0 += dj0*bb;
        if (has2){ pA1 += dj1*a; pB1 += dj1*bb; }
      }
    }
    // epilogue: prime store + e1 for rows rA..rA+has2
    for (int rr=0; rr<=has2; rr++){
      int irow = i0 + rA + rr;
      vf4 pA = rr ? pA1 : pA0;
      vf4 pB = rr ? pB1 : pB0;
      vf4* pp = (vf4*)(prime + (size_t)irow*HDIM);
      pp[lane] = pA;
      if (lane<11) pp[64+lane] = pB;
      const vf4* Xr = (const vf4*)(X + (rA+rr)*308);
      vf4 xo = Xr[lane];
      vf4 q1 = H4[lane], q2 = H4b[lane];
      float ep = xo.x*q1.x+xo.y*q1.y+xo.z*q1.z+xo.w*q1.w
               + pA.x*q2.x+pA.y*q2.y+pA.z*q2.z+pA.w*q2.w;
      if (lane<11){
        vf4 xo2 = Xr[64+lane];
        vf4 q1b = H4[64+lane], q2b = H4b[64+lane];
        ep += xo2.x*q1b.x+xo2.y*q1b.y+xo2.z*q1b.z+xo2.w*q1b.w
            + pB.x*q2b.x+pB.y*q2b.y+pB.z*q2b.z+pB.w*q2b.w;
      }
      ep = wred_sum(ep);
      if (lane==0) e1g[irow] = ep;
    }
  }
}

// ---- K3: 512 blocks: segment softmax over e1 + r1 -------------------------
__global__ __launch_bounds__(256) void k_r1(const float* __restrict__ su,
    const float* __restrict__ sv, const float* __restrict__ spr,
    const float* __restrict__ svp, const float* __restrict__ e1u,
    const float* __restrict__ e1v, const int* __restrict__ uoff,
    const int* __restrict__ voff, float* __restrict__ r1){
  int tid = threadIdx.x, lane = tid & 63, w = tid >> 6;
  int bs = blockIdx.x; int set = bs >> 8; int g = bs & 255;
  const float* x  = set? sv  : su;
  const float* pr = set? svp : spr;
  const float* e  = set? e1v : e1u;
  const int* off  = set? voff: uoff;
  __shared__ float al[2048]; __shared__ float red[4]; __shared__ float shv;
  int ns = off[g], ne = off[g+1]; int n = ne - ns;
  float m = -INFINITY;
  for (int t=ns+tid; t<ne; t+=256) m = fmaxf(m, e[t]);
  m = wred_max(m);
  if (lane==0) red[w]=m;
  __syncthreads();
  if (tid==0) shv = fmaxf(fmaxf(red[0],red[1]),fmaxf(red[2],red[3]));
  __syncthreads();
  float emax = shv;
  float s = 0.f;
  for (int t=tid; t<n; t+=256){ float a = expf(e[ns+t]-emax); if (t<2048) al[t]=a; s += a; }
  s = wred_sum(s);
  __syncthreads();
  if (lane==0) red[w]=s;
  __syncthreads();
  if (tid==0) shv = red[0]+red[1]+red[2]+red[3];
  __syncthreads();
  float inv = 1.f/(shv + 1e-16f);
  float acc[3] = {0.f,0.f,0.f};
  #pragma unroll 4
  for (int nn=0; nn<n; nn++){
    float a = (nn<2048)? al[nn] : expf(e[ns+nn]-emax);
    const float* xr = x  + (size_t)(ns+nn)*HDIM;
    const float* pp = pr + (size_t)(ns+nn)*HDIM;
    #pragma unroll
    for(int u=0;u<3;u++){ int c = tid + u*256; if (c<DDIM){
        float xv = (c<HDIM)? xr[c] : pp[c-HDIM]; acc[u] += a*xv; } }
  }
  #pragma unroll
  for(int u=0;u<3;u++){ int c = tid + u*256; if (c<DDIM) r1[(size_t)bs*DDIM + c] = acc[u]*inv; }
}

// ---- K4: fused GEMM (gates = r1 @ Wih[:,600:].T) + step-2 LSTM pointwise.
// 32 gs x 64 col tile (cols = 4 gates x 16 d), grid 38x16 = 608 blocks. -----
__global__ __launch_bounds__(256) void k_gemm_lstm(const float* __restrict__ r1,
    const float* __restrict__ Wih, const float* __restrict__ gbase,
    const float* __restrict__ c1, float* __restrict__ h2){
  __shared__ __align__(16) float smem[32*68];   // gates phase; K phase aliases
  float* Al = smem;            // 16*36
  float* Bl = smem + 16*36;    // 16*68
  int tid = threadIdx.x;
  int d0  = blockIdx.x*16;     // 38 blocks: d0 = 0..592 (last has 8 valid)
  int gs0 = blockIdx.y*32;
  int tx = tid & 15, ty = tid >> 4;
  float acc[2][4] = {};
  for (int kt=0; kt<600; kt+=16){
    int k = kt + tx;
    bool kok = (k < 600);
    #pragma unroll
    for (int u=0; u<2; u++){
      int rl = ty + u*16;
      Al[tx*36 + rl] = kok ? r1[(size_t)(gs0+rl)*DDIM + k] : 0.f;
    }
    #pragma unroll
    for (int u=0; u<4; u++){
      int cl = ty + u*16;                 // 0..63
      int gate = cl >> 4, dd = cl & 15;
      int d = d0 + dd;
      Bl[tx*68 + cl] = (kok && d < 600)
          ? Wih[(size_t)(gate*600 + d)*1200 + 600 + k] : 0.f;
    }
    __syncthreads();
    #pragma unroll
    for (int kk=0; kk<16; kk++){
      vf2 av = ((const vf2*)(Al + kk*36))[ty];
      vf4 bv = ((const vf4*)(Bl + kk*68))[tx];
      float a[2]={av.x,av.y}, bb[4]={bv.x,bv.y,bv.z,bv.w};
      #pragma unroll
      for(int mm=0;mm<2;mm++)
        #pragma unroll
        for(int nn=0;nn<4;nn++) acc[mm][nn] += a[mm]*bb[nn];
    }
    __syncthreads();
  }
  #pragma unroll
  for (int mm=0; mm<2; mm++){
    vf4 o = {acc[mm][0], acc[mm][1], acc[mm][2], acc[mm][3]};
    ((vf4*)(smem + (ty*2+mm)*68))[tx] = o;
  }
  __syncthreads();
  int d_l = tid & 15, r0 = tid >> 4;
  int d = d0 + d_l;
  if (d < 600){
    float gb_i = gbase[d], gb_f = gbase[600+d], gb_g = gbase[1200+d], gb_o = gbase[1800+d];
    float cc1 = c1[d];
    #pragma unroll
    for (int u=0; u<2; u++){
      int rl = r0 + u*16;
      const float* gr = smem + rl*68;
      float gi = gr[d_l]      + gb_i;
      float gf = gr[16+d_l]   + gb_f;
      float gG = gr[32+d_l]   + gb_g;
      float go = gr[48+d_l]   + gb_o;
      float c  = sigm(gf)*cc1 + sigm(gi)*tanhf(gG);
      h2[(size_t)(gs0+rl)*DDIM + d] = sigm(go)*tanhf(c);
    }
  }
}

// ---- K5: 512 blocks: e2 (in LDS) -> segment softmax -> r2 -> atomicAdd pred
__global__ __launch_bounds__(256) void k_r2(const float* __restrict__ su,
    const float* __restrict__ sv, const float* __restrict__ spr,
    const float* __restrict__ svp, const int* __restrict__ uoff,
    const int* __restrict__ voff, const float* __restrict__ h2,
    const float* __restrict__ pW, float* __restrict__ e2u,
    float* __restrict__ e2v, float* __restrict__ outp){
  int tid = threadIdx.x, lane = tid & 63, w = tid >> 6;
  int bs = blockIdx.x; int set = bs >> 8; int g = bs & 255;
  const float* x  = set? sv  : su;
  const float* pr = set? svp : spr;
  const int* off  = set? voff: uoff;
  float* e2g      = set? e2v : e2u;        // overflow fallback only
  __shared__ float q[DDIM]; __shared__ float e2l[128]; __shared__ float al[128];
  __shared__ float red[4]; __shared__ float shv;
  for (int t=tid; t<DDIM; t+=256) q[t] = h2[(size_t)bs*DDIM + t];
  int ns = off[g], ne = off[g+1]; int n = ne - ns;
  __syncthreads();
  #pragma unroll 2
  for (int node = ns + w; node < ne; node += 4){
    const float* xr = x  + (size_t)node*HDIM;
    const float* pp = pr + (size_t)node*HDIM;
    float d = 0.f;
    #pragma unroll
    for(int c=0;c<10;c++){ int k = lane + 64*c; if (k<DDIM){
        float xv = (k<HDIM)? xr[k] : pp[k-HDIM]; d += xv*q[k]; } }
    d = wred_sum(d);
    if (lane==0){ int t = node-ns; if (t<128) e2l[t] = d; else e2g[node] = d; }
  }
  __syncthreads();
  float m = -INFINITY;
  for (int t=tid; t<n; t+=256) m = fmaxf(m, (t<128)? e2l[t] : e2g[ns+t]);
  m = wred_max(m);
  if (lane==0) red[w]=m;
  __syncthreads();
  if (tid==0) shv = fmaxf(fmaxf(red[0],red[1]),fmaxf(red[2],red[3]));
  __syncthreads();
  float emax = shv;
  float s = 0.f;
  for (int t=tid; t<n; t+=256){
    float a = expf(((t<128)? e2l[t] : e2g[ns+t]) - emax);
    if (t<128) al[t]=a; else e2g[ns+t]=a;
    s += a;
  }
  s = wred_sum(s);
  __syncthreads();
  if (lane==0) red[w]=s;
  __syncthreads();
  if (tid==0) shv = red[0]+red[1]+red[2]+red[3];
  __syncthreads();
  float inv = 1.f/(shv + 1e-16f);
  float acc[3] = {0.f,0.f,0.f};
  #pragma unroll 4
  for (int nn=0; nn<n; nn++){
    float a = (nn<128)? al[nn] : e2g[ns+nn];
    const float* xr = x  + (size_t)(ns+nn)*HDIM;
    const float* pp = pr + (size_t)(ns+nn)*HDIM;
    #pragma unroll
    for(int u=0;u<3;u++){ int c = tid + u*256; if (c<DDIM){
        float xv = (c<HDIM)? xr[c] : pp[c-HDIM]; acc[u] += a*xv; } }
  }
  int hoff = set? 1200 : 0;
  float p = 0.f;
  #pragma unroll
  for(int u=0;u<3;u++){ int c = tid + u*256; if (c<DDIM) p += (acc[u]*inv)*pW[hoff+600+c]; }
  for (int t=tid; t<DDIM; t+=256) p += q[t]*pW[hoff+t];
  p = wred_sum(p);
  __syncthreads();
  if (lane==0) red[w] = p;
  __syncthreads();
  if (tid==0) atomicAdd(&outp[g], red[0]+red[1]+red[2]+red[3]);
}

extern "C" void kernel_launch(void* const* d_in, const int* in_sizes, int n_in,
                              void* d_out, int out_size, void* d_ws, size_t ws_size,
                              hipStream_t stream) {
  const float* solute_x  = (const float*)d_in[0];
  const float* solvent_x = (const float*)d_in[1];
  const int*   ub        = (const int*)d_in[2];
  const int*   vb        = (const int*)d_in[3];
  const float* Wih  = (const float*)d_in[5];
  const float* Whh  = (const float*)d_in[6];
  const float* b_ih = (const float*)d_in[7];
  const float* b_hh = (const float*)d_in[8];
  const float* pW   = (const float*)d_in[9];
  const float* pb   = (const float*)d_in[10];

  int Nu = in_sizes[0] / HDIM;
  int Nv = in_sizes[1] / HDIM;

  float* out = (float*)d_out;
  int predn = out_size - Nu*Nv;        // = 256
  float* mapbase = out + predn;

  float* ws = (float*)d_ws;
  float* su    = ws;
  float* sv    = su    + (size_t)Nu*HDIM;
  float* spr   = sv    + (size_t)Nv*HDIM;
  float* svp   = spr   + (size_t)Nu*HDIM;
  float* e1u   = svp   + (size_t)Nv*HDIM;  // Nu
  float* e1v   = e1u   + Nu;               // Nv
  float* h1    = e1v   + Nv;               // 600
  float* c1    = h1    + DDIM;             // 600
  float* r1    = c1    + DDIM;             // 512*600
  float* gbase = r1    + 512*DDIM;         // 2400
  float* h2    = gbase + 2400;             // 512*600
  int*   uoff  = (int*)(h2 + 512*DDIM);    // 257
  int*   voff  = uoff + 257;               // 257

  k_norm_off<<<dim3((Nu+Nv)/4 + 1 + 600), dim3(256), 0, stream>>>(
      solute_x, solvent_x, su, sv, Nu, Nv, ub, vb, uoff, voff,
      b_ih, b_hh, h1, c1, pb, out, Wih, Whh, gbase);
  // 2048 compute blocks (1 wave = 1 row pair) interleaved with Nu fill blocks.
  k_pair<<<dim3((Nu+Nv)/8 + Nu), dim3(256), 0, stream>>>(
      su, sv, ub, vb, uoff, voff, spr, svp, e1u, e1v, h1, mapbase, Nu, Nv);
  k_r1<<<dim3(512), dim3(256), 0, stream>>>(
      su, sv, spr, svp, e1u, e1v, uoff, voff, r1);
  k_gemm_lstm<<<dim3(38, 16), dim3(256), 0, stream>>>(r1, Wih, gbase, c1, h2);
  k_r2<<<dim3(512), dim3(256), 0, stream>>>(
      su, sv, spr, svp, uoff, voff, h2, pW, e1u, e1v, out);
}

// Round 3
// 566.361 us; speedup vs baseline: 1.0298x; 1.0048x over previous
//
#include <hip/hip_runtime.h>
#include <math.h>

// Problem constants: H=300, D=600, B=256 graphs, Nu=Nv=8192, batch SORTED.
#define HDIM 300
#define DDIM 600
#define NGR  256

typedef float vf4 __attribute__((ext_vector_type(4)));
typedef float vf2 __attribute__((ext_vector_type(2)));

__device__ __forceinline__ float wred_sum(float v){
  #pragma unroll
  for(int o=32;o;o>>=1) v += __shfl_xor(v,o,64);
  return v;
}
__device__ __forceinline__ float wred_max(float v){
  #pragma unroll
  for(int o=32;o;o>>=1) v = fmaxf(v,__shfl_xor(v,o,64));
  return v;
}
__device__ __forceinline__ float sigm(float x){ return 1.f/(1.f+expf(-x)); }

// Zero-fill map row i outside its in-graph span [js,je) (NT float4 stores).
__device__ __forceinline__ void fill_row(int i, const int* __restrict__ ub,
    const int* __restrict__ voff, float* __restrict__ mapbase, int Nv, int tid){
  int g = ub[i];
  int js = voff[g], je = voff[g+1];
  float* mrow = mapbase + (size_t)i*Nv;
  const vf4 z4 = {0.f,0.f,0.f,0.f};
  int nf4 = Nv >> 2;
  for (int q4=tid; q4<nf4; q4+=256){
    int j0 = q4*4;
    if (j0+4 <= js || j0 >= je){
      __builtin_nontemporal_store(z4, (vf4*)(mrow + j0));
    } else {
      #pragma unroll
      for(int u=0;u<4;u++){ int j=j0+u; if (j<js || j>=je) mrow[j]=0.f; }
    }
  }
}

// ---- K1: blocks [0,NBn): l2-normalize rows (4 waves/block);
//  NBn: offsets (binary search) + step-1 LSTM closed form + out init;
//  (NBn, NBn+600]: gbase (recomputes bias-only h1 locally -> no cross-block dep).
__global__ __launch_bounds__(256) void k_norm_off(const float* __restrict__ xu,
    const float* __restrict__ xv, float* __restrict__ su, float* __restrict__ sv,
    int Nu, int Nv, const int* __restrict__ ub, const int* __restrict__ vb,
    int* __restrict__ uoff, int* __restrict__ voff,
    const float* __restrict__ b_ih, const float* __restrict__ b_hh,
    float* __restrict__ h1, float* __restrict__ c1,
    const float* __restrict__ pb, float* __restrict__ outp,
    const float* __restrict__ Wih, const float* __restrict__ Whh,
    float* __restrict__ gbase){
  int NBn = (Nu + Nv) >> 2;
  int b = blockIdx.x;
  int tid = threadIdx.x, lane = tid & 63, w = tid >> 6;
  if (b == NBn){
    int t = tid;
    if (t < NGR){
      int lo=0, hi=Nu;
      while(lo<hi){ int m=(lo+hi)>>1; if (ub[m] < t) lo=m+1; else hi=m; }
      uoff[t]=lo;
      lo=0; hi=Nv;
      while(lo<hi){ int m=(lo+hi)>>1; if (vb[m] < t) lo=m+1; else hi=m; }
      voff[t]=lo;
      if (t==0){ uoff[NGR]=Nu; voff[NGR]=Nv; }
      outp[t] = pb[0];
    }
    for (int d=tid; d<DDIM; d+=256){
      float gi = b_ih[d]      + b_hh[d];
      float gg = b_ih[1200+d] + b_hh[1200+d];
      float go = b_ih[1800+d] + b_hh[1800+d];
      float c  = sigm(gi)*tanhf(gg);       // f*c0 = 0
      c1[d]=c; h1[d]=sigm(go)*tanhf(c);
    }
    return;
  }
  if (b > NBn){                            // gbase blocks
    __shared__ float h1l[DDIM];
    for (int d=tid; d<DDIM; d+=256){       // recompute bias-only h1 locally
      float gi = b_ih[d]      + b_hh[d];
      float gg = b_ih[1200+d] + b_hh[1200+d];
      float go = b_ih[1800+d] + b_hh[1800+d];
      float c  = sigm(gi)*tanhf(gg);
      h1l[d]   = sigm(go)*tanhf(c);
    }
    __syncthreads();
    int n = (b - NBn - 1)*4 + w;           // 600 blocks x 4 waves = 2400 rows
    const float* wi = Wih + (size_t)n*1200;
    const float* wh = Whh + (size_t)n*600;
    float s = 0.f;
    for (int k=lane; k<DDIM; k+=64) s += h1l[k]*(wi[k] + wh[k]);
    s = wred_sum(s);
    if (lane==0) gbase[n] = s + b_ih[n] + b_hh[n];
    return;
  }
  int wid = b*4 + w;
  const float* src; float* dst;
  if (wid < Nu){ src = xu + (size_t)wid*HDIM; dst = su + (size_t)wid*HDIM; }
  else         { src = xv + (size_t)(wid-Nu)*HDIM; dst = sv + (size_t)(wid-Nu)*HDIM; }
  const vf4* s4 = (const vf4*)src;
  vf4 A = s4[lane];
  vf4 Bv = (lane<11)? s4[64+lane] : (vf4){0.f,0.f,0.f,0.f};
  float s = A.x*A.x+A.y*A.y+A.z*A.z+A.w*A.w + Bv.x*Bv.x+Bv.y*Bv.y+Bv.z*Bv.z+Bv.w*Bv.w;
  s = wred_sum(s);
  float inv = 1.f / fmaxf(sqrtf(s), 1e-12f);
  vf4* d4 = (vf4*)dst;
  d4[lane] = A*inv;
  if (lane<11) d4[64+lane] = Bv*inv;
}

// ---- K2 (R3): R0's proven k_prime structure, but TWO own rows per compute
// block: the coalesced partner-row read (oA/oB) is reused for 2 dots + 2
// prime accumulations -> compute blocks halve (16384->8192), partner L2
// traffic halves (~630->315MB). Boundary-straddling pairs (g0!=g1, <=255 of
// 8192) run the j-loop twice in single-row mode. Fill stays interleaved
// inside this kernel (R7 lesson), exact 1:1 (even=compute, odd=fill).
__global__ __launch_bounds__(256) void k_prime2(const float* __restrict__ su,
    const float* __restrict__ sv, const int* __restrict__ ub,
    const int* __restrict__ vb, const int* __restrict__ uoff,
    const int* __restrict__ voff, float* __restrict__ spr,
    float* __restrict__ svp, float* __restrict__ e1u, float* __restrict__ e1v,
    const float* __restrict__ h1, float* __restrict__ mapbase, int Nu, int Nv){
  int b = blockIdx.x;
  int tid = threadIdx.x, lane = tid & 63, w = tid >> 6;
  if (b & 1){ fill_row(b>>1, ub, voff, mapbase, Nv, tid); return; }
  int p  = b >> 1;                         // pair id: combined rows 2p, 2p+1
  int r0 = 2*p;
  bool isU = (r0 < Nu);                    // Nu even -> pairs never straddle U/V
  int i0 = isU ? r0 : r0 - Nu;
  const float* xa = isU ? su : sv;
  const float* xb = isU ? sv : su;
  const int* mybatch = isU ? ub : vb;
  const int* ooff    = isU ? voff : uoff;
  float* prime = isU ? spr : svp;
  float* eout  = isU ? e1u : e1v;

  __shared__ __align__(16) float xrow[2*304];
  __shared__ __align__(16) float prl[8*304];   // [wave][row][304]
  __shared__ float qv[2*HDIM];
  __shared__ float red[8];
  for (int t=tid; t<2*HDIM; t+=256){           // both own rows (contiguous)
    int rr = t/HDIM, c = t-rr*HDIM;
    xrow[rr*304+c] = xa[(size_t)i0*HDIM + t];
  }
  for (int t=tid; t<2*HDIM; t+=256) qv[t] = h1[t];
  int g0 = mybatch[i0], g1 = mybatch[i0+1];
  int nsub = (g0==g1)? 1 : 2;
  __syncthreads();

  const vf4* x40 = (const vf4*)xrow;
  const vf4* x41 = (const vf4*)(xrow+304);
  vf4 xA0 = x40[lane], xA1 = x41[lane];
  vf4 xB0 = (lane<11)? x40[64+lane] : (vf4){0.f,0.f,0.f,0.f};
  vf4 xB1 = (lane<11)? x41[64+lane] : (vf4){0.f,0.f,0.f,0.f};

  vf4 prA0={0,0,0,0}, prB0={0,0,0,0}, prA1={0,0,0,0}, prB1={0,0,0,0};
  for (int sub=0; sub<nsub; sub++){
    int g   = (sub==0)? g0 : g1;
    bool do0 = (nsub==1) || (sub==0);
    bool do1 = (nsub==1) || (sub==1);
    int js = ooff[g], je = ooff[g+1];
    for (int j = js + w; j < je; j += 4){
      const vf4* orow = (const vf4*)(xb + (size_t)j*HDIM);
      vf4 oA = orow[lane];
      vf4 oB = (lane<11)? orow[64+lane] : (vf4){0.f,0.f,0.f,0.f};
      if (do0){
        float d = oA.x*xA0.x + oA.y*xA0.y + oA.z*xA0.z + oA.w*xA0.w
                + oB.x*xB0.x + oB.y*xB0.y + oB.z*xB0.z + oB.w*xB0.w;
        d = wred_sum(d);
        if (isU && lane==0) mapbase[(size_t)i0*Nv + j] = d;
        prA0 += d*oA; prB0 += d*oB;
      }
      if (do1){
        float d = oA.x*xA1.x + oA.y*xA1.y + oA.z*xA1.z + oA.w*xA1.w
                + oB.x*xB1.x + oB.y*xB1.y + oB.z*xB1.z + oB.w*xB1.w;
        d = wred_sum(d);
        if (isU && lane==0) mapbase[(size_t)(i0+1)*Nv + j] = d;
        prA1 += d*oA; prB1 += d*oB;
      }
    }
  }
  vf4* p40 = (vf4*)(prl + w*608);
  vf4* p41 = (vf4*)(prl + w*608 + 304);
  p40[lane] = prA0; if (lane<11) p40[64+lane] = prB0;
  p41[lane] = prA1; if (lane<11) p41[64+lane] = prB1;
  __syncthreads();
  float ep0 = 0.f, ep1 = 0.f;
  for (int t=tid; t<HDIM; t+=256){
    float s0 = prl[t]     + prl[608+t]  + prl[1216+t] + prl[1824+t];
    float s1 = prl[304+t] + prl[912+t]  + prl[1520+t] + prl[2128+t];
    prime[(size_t)i0*HDIM + t]     = s0;
    prime[(size_t)(i0+1)*HDIM + t] = s1;
    ep0 += xrow[t]*qv[t]     + s0*qv[HDIM+t];
    ep1 += xrow[304+t]*qv[t] + s1*qv[HDIM+t];
  }
  ep0 = wred_sum(ep0);
  ep1 = wred_sum(ep1);
  if (lane==0){ red[w] = ep0; red[4+w] = ep1; }
  __syncthreads();
  if (tid==0) eout[i0]   = red[0]+red[1]+red[2]+red[3];
  if (tid==1) eout[i0+1] = red[4]+red[5]+red[6]+red[7];
}

// ---- K3: 512 blocks: segment softmax over e1 + r1 -------------------------
__global__ __launch_bounds__(256) void k_r1(const float* __restrict__ su,
    const float* __restrict__ sv, const float* __restrict__ spr,
    const float* __restrict__ svp, const float* __restrict__ e1u,
    const float* __restrict__ e1v, const int* __restrict__ uoff,
    const int* __restrict__ voff, float* __restrict__ r1){
  int tid = threadIdx.x, lane = tid & 63, w = tid >> 6;
  int bs = blockIdx.x; int set = bs >> 8; int g = bs & 255;
  const float* x  = set? sv  : su;
  const float* pr = set? svp : spr;
  const float* e  = set? e1v : e1u;
  const int* off  = set? voff: uoff;
  __shared__ float al[2048]; __shared__ float red[4]; __shared__ float shv;
  int ns = off[g], ne = off[g+1]; int n = ne - ns;
  float m = -INFINITY;
  for (int t=ns+tid; t<ne; t+=256) m = fmaxf(m, e[t]);
  m = wred_max(m);
  if (lane==0) red[w]=m;
  __syncthreads();
  if (tid==0) shv = fmaxf(fmaxf(red[0],red[1]),fmaxf(red[2],red[3]));
  __syncthreads();
  float emax = shv;
  float s = 0.f;
  for (int t=tid; t<n; t+=256){ float a = expf(e[ns+t]-emax); if (t<2048) al[t]=a; s += a; }
  s = wred_sum(s);
  __syncthreads();
  if (lane==0) red[w]=s;
  __syncthreads();
  if (tid==0) shv = red[0]+red[1]+red[2]+red[3];
  __syncthreads();
  float inv = 1.f/(shv + 1e-16f);
  float acc[3] = {0.f,0.f,0.f};
  #pragma unroll 4
  for (int nn=0; nn<n; nn++){
    float a = (nn<2048)? al[nn] : expf(e[ns+nn]-emax);
    const float* xr = x  + (size_t)(ns+nn)*HDIM;
    const float* pp = pr + (size_t)(ns+nn)*HDIM;
    #pragma unroll
    for(int u=0;u<3;u++){ int c = tid + u*256; if (c<DDIM){
        float xv = (c<HDIM)? xr[c] : pp[c-HDIM]; acc[u] += a*xv; } }
  }
  #pragma unroll
  for(int u=0;u<3;u++){ int c = tid + u*256; if (c<DDIM) r1[(size_t)bs*DDIM + c] = acc[u]*inv; }
}

// ---- K4: fused GEMM (gates = r1 @ Wih[:,600:].T) + step-2 LSTM pointwise.
// 32 gs x 64 col tile (cols = 4 gates x 16 d), grid 38x16 = 608 blocks. -----
__global__ __launch_bounds__(256) void k_gemm_lstm(const float* __restrict__ r1,
    const float* __restrict__ Wih, const float* __restrict__ gbase,
    const float* __restrict__ c1, float* __restrict__ h2){
  __shared__ __align__(16) float smem[32*68];   // gates phase; K phase aliases
  float* Al = smem;            // 16*36
  float* Bl = smem + 16*36;    // 16*68
  int tid = threadIdx.x;
  int d0  = blockIdx.x*16;     // 38 blocks: d0 = 0..592 (last has 8 valid)
  int gs0 = blockIdx.y*32;
  int tx = tid & 15, ty = tid >> 4;
  float acc[2][4] = {};
  for (int kt=0; kt<600; kt+=16){
    int k = kt + tx;
    bool kok = (k < 600);
    #pragma unroll
    for (int u=0; u<2; u++){
      int rl = ty + u*16;
      Al[tx*36 + rl] = kok ? r1[(size_t)(gs0+rl)*DDIM + k] : 0.f;
    }
    #pragma unroll
    for (int u=0; u<4; u++){
      int cl = ty + u*16;                 // 0..63
      int gate = cl >> 4, dd = cl & 15;
      int d = d0 + dd;
      Bl[tx*68 + cl] = (kok && d < 600)
          ? Wih[(size_t)(gate*600 + d)*1200 + 600 + k] : 0.f;
    }
    __syncthreads();
    #pragma unroll
    for (int kk=0; kk<16; kk++){
      vf2 av = ((const vf2*)(Al + kk*36))[ty];
      vf4 bv = ((const vf4*)(Bl + kk*68))[tx];
      float a[2]={av.x,av.y}, bb[4]={bv.x,bv.y,bv.z,bv.w};
      #pragma unroll
      for(int mm=0;mm<2;mm++)
        #pragma unroll
        for(int nn=0;nn<4;nn++) acc[mm][nn] += a[mm]*bb[nn];
    }
    __syncthreads();
  }
  #pragma unroll
  for (int mm=0; mm<2; mm++){
    vf4 o = {acc[mm][0], acc[mm][1], acc[mm][2], acc[mm][3]};
    ((vf4*)(smem + (ty*2+mm)*68))[tx] = o;
  }
  __syncthreads();
  int d_l = tid & 15, r0 = tid >> 4;
  int d = d0 + d_l;
  if (d < 600){
    float gb_i = gbase[d], gb_f = gbase[600+d], gb_g = gbase[1200+d], gb_o = gbase[1800+d];
    float cc1 = c1[d];
    #pragma unroll
    for (int u=0; u<2; u++){
      int rl = r0 + u*16;
      const float* gr = smem + rl*68;
      float gi = gr[d_l]      + gb_i;
      float gf = gr[16+d_l]   + gb_f;
      float gG = gr[32+d_l]   + gb_g;
      float go = gr[48+d_l]   + gb_o;
      float c  = sigm(gf)*cc1 + sigm(gi)*tanhf(gG);
      h2[(size_t)(gs0+rl)*DDIM + d] = sigm(go)*tanhf(c);
    }
  }
}

// ---- K5: 512 blocks: e2 (in LDS) -> segment softmax -> r2 -> atomicAdd pred
__global__ __launch_bounds__(256) void k_r2(const float* __restrict__ su,
    const float* __restrict__ sv, const float* __restrict__ spr,
    const float* __restrict__ svp, const int* __restrict__ uoff,
    const int* __restrict__ voff, const float* __restrict__ h2,
    const float* __restrict__ pW, float* __restrict__ e2u,
    float* __restrict__ e2v, float* __restrict__ outp){
  int tid = threadIdx.x, lane = tid & 63, w = tid >> 6;
  int bs = blockIdx.x; int set = bs >> 8; int g = bs & 255;
  const float* x  = set? sv  : su;
  const float* pr = set? svp : spr;
  const int* off  = set? voff: uoff;
  float* e2g      = set? e2v : e2u;        // overflow fallback only
  __shared__ float q[DDIM]; __shared__ float e2l[128]; __shared__ float al[128];
  __shared__ float red[4]; __shared__ float shv;
  for (int t=tid; t<DDIM; t+=256) q[t] = h2[(size_t)bs*DDIM + t];
  int ns = off[g], ne = off[g+1]; int n = ne - ns;
  __syncthreads();
  #pragma unroll 2
  for (int node = ns + w; node < ne; node += 4){
    const float* xr = x  + (size_t)node*HDIM;
    const float* pp = pr + (size_t)node*HDIM;
    float d = 0.f;
    #pragma unroll
    for(int c=0;c<10;c++){ int k = lane + 64*c; if (k<DDIM){
        float xv = (k<HDIM)? xr[k] : pp[k-HDIM]; d += xv*q[k]; } }
    d = wred_sum(d);
    if (lane==0){ int t = node-ns; if (t<128) e2l[t] = d; else e2g[node] = d; }
  }
  __syncthreads();
  float m = -INFINITY;
  for (int t=tid; t<n; t+=256) m = fmaxf(m, (t<128)? e2l[t] : e2g[ns+t]);
  m = wred_max(m);
  if (lane==0) red[w]=m;
  __syncthreads();
  if (tid==0) shv = fmaxf(fmaxf(red[0],red[1]),fmaxf(red[2],red[3]));
  __syncthreads();
  float emax = shv;
  float s = 0.f;
  for (int t=tid; t<n; t+=256){
    float a = expf(((t<128)? e2l[t] : e2g[ns+t]) - emax);
    if (t<128) al[t]=a; else e2g[ns+t]=a;
    s += a;
  }
  s = wred_sum(s);
  __syncthreads();
  if (lane==0) red[w]=s;
  __syncthreads();
  if (tid==0) shv = red[0]+red[1]+red[2]+red[3];
  __syncthreads();
  float inv = 1.f/(shv + 1e-16f);
  float acc[3] = {0.f,0.f,0.f};
  #pragma unroll 4
  for (int nn=0; nn<n; nn++){
    float a = (nn<128)? al[nn] : e2g[ns+nn];
    const float* xr = x  + (size_t)(ns+nn)*HDIM;
    const float* pp = pr + (size_t)(ns+nn)*HDIM;
    #pragma unroll
    for(int u=0;u<3;u++){ int c = tid + u*256; if (c<DDIM){
        float xv = (c<HDIM)? xr[c] : pp[c-HDIM]; acc[u] += a*xv; } }
  }
  int hoff = set? 1200 : 0;
  float p = 0.f;
  #pragma unroll
  for(int u=0;u<3;u++){ int c = tid + u*256; if (c<DDIM) p += (acc[u]*inv)*pW[hoff+600+c]; }
  for (int t=tid; t<DDIM; t+=256) p += q[t]*pW[hoff+t];
  p = wred_sum(p);
  __syncthreads();
  if (lane==0) red[w] = p;
  __syncthreads();
  if (tid==0) atomicAdd(&outp[g], red[0]+red[1]+red[2]+red[3]);
}

extern "C" void kernel_launch(void* const* d_in, const int* in_sizes, int n_in,
                              void* d_out, int out_size, void* d_ws, size_t ws_size,
                              hipStream_t stream) {
  const float* solute_x  = (const float*)d_in[0];
  const float* solvent_x = (const float*)d_in[1];
  const int*   ub        = (const int*)d_in[2];
  const int*   vb        = (const int*)d_in[3];
  const float* Wih  = (const float*)d_in[5];
  const float* Whh  = (const float*)d_in[6];
  const float* b_ih = (const float*)d_in[7];
  const float* b_hh = (const float*)d_in[8];
  const float* pW   = (const float*)d_in[9];
  const float* pb   = (const float*)d_in[10];

  int Nu = in_sizes[0] / HDIM;
  int Nv = in_sizes[1] / HDIM;

  float* out = (float*)d_out;
  int predn = out_size - Nu*Nv;        // = 256
  float* mapbase = out + predn;

  float* ws = (float*)d_ws;
  float* su    = ws;
  float* sv    = su    + (size_t)Nu*HDIM;
  float* spr   = sv    + (size_t)Nv*HDIM;
  float* svp   = spr   + (size_t)Nu*HDIM;
  float* e1u   = svp   + (size_t)Nv*HDIM;  // Nu
  float* e1v   = e1u   + Nu;               // Nv
  float* h1    = e1v   + Nv;               // 600
  float* c1    = h1    + DDIM;             // 600
  float* r1    = c1    + DDIM;             // 512*600
  float* gbase = r1    + 512*DDIM;         // 2400
  float* h2    = gbase + 2400;             // 512*600
  int*   uoff  = (int*)(h2 + 512*DDIM);    // 257
  int*   voff  = uoff + 257;               // 257

  k_norm_off<<<dim3((Nu+Nv)/4 + 1 + 600), dim3(256), 0, stream>>>(
      solute_x, solvent_x, su, sv, Nu, Nv, ub, vb, uoff, voff,
      b_ih, b_hh, h1, c1, pb, out, Wih, Whh, gbase);
  // (Nu+Nv)/2 compute blocks (2 rows each, even b) + Nu fill blocks (odd b).
  k_prime2<<<dim3((Nu+Nv)/2 + Nu), dim3(256), 0, stream>>>(
      su, sv, ub, vb, uoff, voff, spr, svp, e1u, e1v, h1, mapbase, Nu, Nv);
  k_r1<<<dim3(512), dim3(256), 0, stream>>>(
      su, sv, spr, svp, e1u, e1v, uoff, voff, r1);
  k_gemm_lstm<<<dim3(38, 16), dim3(256), 0, stream>>>(r1, Wih, gbase, c1, h2);
  k_r2<<<dim3(512), dim3(256), 0, stream>>>(
      su, sv, spr, svp, uoff, voff, h2, pW, e1u, e1v, out);
}